// Round 3
// baseline (264.768 us; speedup 1.0000x reference)
//
#include <hip/hip_runtime.h>

#define ITERS 20
#define EPS 1e-9f

typedef float v2f __attribute__((ext_vector_type(2)));

// TWO waves per 64x64 matrix: wave-half w owns 32 columns; lane (bi,bj) owns an
// 8-row x 4-col tile (rows 8bi..8bi+7, cols 32w+4bj..+3) = 32 fp32 E regs/lane.
// Halving per-lane E (vs 64) keeps total regs <=~64 -> ~8 waves/SIMD (2x the
// previous occupancy) and eliminates the AGPR split of the 1-wave version.
//
// Sinkhorn iterate M = E .* (u v^T): only u,v update; E stays in registers.
// Row sums need a cross-wave add: 8-float LDS exchange + __syncthreads per
// iteration (double-buffered slots). Col sums are wave-local. Both waves
// recompute u identically (p_half0 + p_half1 is commutative), so u needs no
// extra sync. All reduces are VALU (DPP / permlane swaps), no DS in-loop
// except the 8-float exchange.

template <int CTRL>
__device__ __forceinline__ float dpp_add(float x) {
    int yi = __builtin_amdgcn_update_dpp(0, __float_as_int(x), CTRL, 0xf, 0xf, true);
    return x + __int_as_float(yi);
}

#if __has_builtin(__builtin_amdgcn_permlane16_swap)
// identical inputs: r0+r1 == xor16 butterfly all-reduce, pure VALU
__device__ __forceinline__ float xadd16(float x) {
    unsigned u = __float_as_uint(x);
    auto r = __builtin_amdgcn_permlane16_swap(u, u, false, false);
    return __uint_as_float(r[0]) + __uint_as_float(r[1]);
}
#else
__device__ __forceinline__ float xadd16(float x) {
    // ds_swizzle xor16: offset = (16<<10) | 0x1F
    return x + __int_as_float(__builtin_amdgcn_ds_swizzle(__float_as_int(x), 0x401F));
}
#endif

#if __has_builtin(__builtin_amdgcn_permlane32_swap)
__device__ __forceinline__ float xadd32(float x) {
    unsigned u = __float_as_uint(x);
    auto r = __builtin_amdgcn_permlane32_swap(u, u, false, false);
    return __uint_as_float(r[0]) + __uint_as_float(r[1]);
}
#else
__device__ __forceinline__ float xadd32(float x) {
    return x + __shfl_xor(x, 32, 64);
}
#endif

__global__ __launch_bounds__(256, 6) void sinkhorn_kernel(
        const float* __restrict__ x, float* __restrict__ out, int nmat) {
    // [slot][matInBlock][half][row] — double-buffered row-sum exchange (4 KB)
    __shared__ float xch[2][2][2][64];

    const int lane  = threadIdx.x & 63;
    const int wave  = threadIdx.x >> 6;
    const int mslot = wave >> 1;     // matrix within block (0/1)
    const int w     = wave & 1;      // column half (0/1)
    int mat = blockIdx.x * 2 + mslot;
    if (mat >= nmat) mat = nmat - 1; // clamp: keep barriers convergent (nmat even anyway)
    const int bi = lane >> 3;        // row-group 0..7 (lane bits 3-5)
    const int bj = lane & 7;         // col-group 0..7 (lane bits 0-2)

    const float4* __restrict__ xin = (const float4*)(x + (size_t)mat * 4096);

    // Load 8x4 tile (one float4 per row), apply exp, keep as float2 pairs.
    v2f b2[8][2];
    #pragma unroll
    for (int r = 0; r < 8; ++r) {
        float4 t = xin[(8 * bi + r) * 16 + 8 * w + bj];
        b2[r][0] = (v2f){__expf(t.x), __expf(t.y)};
        b2[r][1] = (v2f){__expf(t.z), __expf(t.w)};
    }

    float uu[8];
    v2f   vv2[2];
    #pragma unroll
    for (int i = 0; i < 8; ++i) uu[i] = 1.0f;
    vv2[0] = (v2f){1.0f, 1.0f};
    vv2[1] = (v2f){1.0f, 1.0f};

    for (int it = 0; it < ITERS; ++it) {
        const int slot = it & 1;

        // ---- row phase: p_i = sum_j E[i,j] v_j over own 4 cols ----
        float p[8];
        #pragma unroll
        for (int r = 0; r < 8; ++r) {
            v2f s2 = b2[r][0] * vv2[0];
            s2 += b2[r][1] * vv2[1];
            p[r] = s2.x + s2.y;
        }
        // all-reduce across the 8 bj lanes (lane bits 0-2) — pure DPP
        #pragma unroll
        for (int r = 0; r < 8; ++r) p[r] = dpp_add<0xB1>(p[r]);   // quad_perm xor1
        #pragma unroll
        for (int r = 0; r < 8; ++r) p[r] = dpp_add<0x4E>(p[r]);   // quad_perm xor2
        #pragma unroll
        for (int r = 0; r < 8; ++r) p[r] = dpp_add<0x141>(p[r]);  // row_half_mirror = xor7

        // cross-wave exchange of the 64 per-half row sums
        if (bj == 0) {
            #pragma unroll
            for (int r = 0; r < 8; ++r) xch[slot][mslot][w][bi * 8 + r] = p[r];
        }
        __syncthreads();
        #pragma unroll
        for (int r = 0; r < 8; ++r) p[r] += xch[slot][mslot][1 - w][bi * 8 + r];

        #pragma unroll
        for (int r = 0; r < 8; ++r) {
            float S = fmaf(uu[r], p[r], EPS);      // rowsum + eps
            uu[r] *= __builtin_amdgcn_rcpf(S);
        }

        // ---- col phase: q_j = sum_i E[i,j] u_i (wave-local cols) ----
        // split accumulators to halve the dependent-FMA chain
        v2f qe0 = b2[0][0] * uu[0];
        v2f qe1 = b2[0][1] * uu[0];
        v2f qo0 = b2[1][0] * uu[1];
        v2f qo1 = b2[1][1] * uu[1];
        #pragma unroll
        for (int r = 2; r < 8; r += 2) {
            qe0 += b2[r][0] * uu[r];
            qe1 += b2[r][1] * uu[r];
            qo0 += b2[r + 1][0] * uu[r + 1];
            qo1 += b2[r + 1][1] * uu[r + 1];
        }
        v2f q0 = qe0 + qo0;
        v2f q1 = qe1 + qo1;

        // all-reduce across the 8 bi lanes (lane bits 3-5) — all VALU
        float qa = dpp_add<0x128>(q0.x);   // row_ror:8 = xor8
        float qb = dpp_add<0x128>(q0.y);
        float qc = dpp_add<0x128>(q1.x);
        float qd = dpp_add<0x128>(q1.y);
        qa = xadd16(qa); qb = xadd16(qb); qc = xadd16(qc); qd = xadd16(qd);
        qa = xadd32(qa); qb = xadd32(qb); qc = xadd32(qc); qd = xadd32(qd);

        float Ta = fmaf(vv2[0].x, qa, EPS);
        float Tb = fmaf(vv2[0].y, qb, EPS);
        float Tc = fmaf(vv2[1].x, qc, EPS);
        float Td = fmaf(vv2[1].y, qd, EPS);
        vv2[0].x *= __builtin_amdgcn_rcpf(Ta);
        vv2[0].y *= __builtin_amdgcn_rcpf(Tb);
        vv2[1].x *= __builtin_amdgcn_rcpf(Tc);
        vv2[1].y *= __builtin_amdgcn_rcpf(Td);
    }

    // ---- epilogue: out = E .* (u v^T) ----
    float4* __restrict__ o = (float4*)(out + (size_t)mat * 4096);
    #pragma unroll
    for (int r = 0; r < 8; ++r) {
        v2f w0 = b2[r][0] * (vv2[0] * uu[r]);
        v2f w1 = b2[r][1] * (vv2[1] * uu[r]);
        float4 t;
        t.x = w0.x; t.y = w0.y; t.z = w1.x; t.w = w1.y;
        o[(8 * bi + r) * 16 + 8 * w + bj] = t;
    }
}

extern "C" void kernel_launch(void* const* d_in, const int* in_sizes, int n_in,
                              void* d_out, int out_size, void* d_ws, size_t ws_size,
                              hipStream_t stream) {
    const float* x = (const float*)d_in[0];
    float* out = (float*)d_out;
    const int nmat = in_sizes[0] / 4096;          // 8192 matrices of 64x64
    const int blocks = (nmat + 1) / 2;            // 2 matrices (4 waves) per block
    sinkhorn_kernel<<<blocks, 256, 0, stream>>>(x, out, nmat);
}

// Round 5
// 248.464 us; speedup vs baseline: 1.0656x; 1.0656x over previous
//
#include <hip/hip_runtime.h>

#define ITERS 20
#define EPS 1e-9f

typedef float v2f __attribute__((ext_vector_type(2)));

// One wave (64 lanes) per 64x64 matrix. Lane (bi,bj) owns the 8x8 sub-block
// rows [8bi,8bi+8), cols [8bj,8bj+8) = 64 fp32 E regs/lane. Sinkhorn iterate
// M = E .* (u v^T): only u,v update; E stays in registers.
//
// This revision pins the packed-fp32 path with inline asm (v_pk_mul/fma/add
// _f32, incl. op_sel broadcasts for the u-scaled col matvec) and simplifies
// the scale updates to u = rcp(p + eps) (algebraically equal to the reference
// update up to O(eps) ~ 1e-9). All cross-lane reduces stay on the VALU pipe
// (fused DPP adds + permlane16/32_swap). No LDS, no barriers.

template <int CTRL>
__device__ __forceinline__ float dpp_add(float x) {
    int yi = __builtin_amdgcn_update_dpp(0, __float_as_int(x), CTRL, 0xf, 0xf, true);
    return x + __int_as_float(yi);
}

#if __has_builtin(__builtin_amdgcn_permlane16_swap)
// identical inputs: r0+r1 == xor16 butterfly all-reduce, pure VALU
__device__ __forceinline__ float xadd16(float x) {
    unsigned u = __float_as_uint(x);
    auto r = __builtin_amdgcn_permlane16_swap(u, u, false, false);
    return __uint_as_float(r[0]) + __uint_as_float(r[1]);
}
#else
__device__ __forceinline__ float xadd16(float x) {
    return x + __int_as_float(__builtin_amdgcn_ds_swizzle(__float_as_int(x), 0x401F));
}
#endif

#if __has_builtin(__builtin_amdgcn_permlane32_swap)
__device__ __forceinline__ float xadd32(float x) {
    unsigned u = __float_as_uint(x);
    auto r = __builtin_amdgcn_permlane32_swap(u, u, false, false);
    return __uint_as_float(r[0]) + __uint_as_float(r[1]);
}
#else
__device__ __forceinline__ float xadd32(float x) {
    return x + __shfl_xor(x, 32, 64);
}
#endif

// ---- pinned packed-fp32 ops (also forces VGPR residency of operands) ----
__device__ __forceinline__ v2f pk_mul(v2f a, v2f b) {
    v2f d;
    asm("v_pk_mul_f32 %0, %1, %2" : "=v"(d) : "v"(a), "v"(b));
    return d;
}
__device__ __forceinline__ v2f pk_fma(v2f a, v2f b, v2f c) {
    v2f d;
    asm("v_pk_fma_f32 %0, %1, %2, %3" : "=v"(d) : "v"(a), "v"(b), "v"(c));
    return d;
}
__device__ __forceinline__ v2f pk_add(v2f a, v2f b) {
    v2f d;
    asm("v_pk_add_f32 %0, %1, %2" : "=v"(d) : "v"(a), "v"(b));
    return d;
}
// acc += a * broadcast(lo(u2)) : src1 lo half replicated to both result lanes
__device__ __forceinline__ v2f pk_fma_bl(v2f a, v2f u2, v2f c) {
    v2f d;
    asm("v_pk_fma_f32 %0, %1, %2, %3 op_sel:[0,0,0] op_sel_hi:[1,0,1]"
        : "=v"(d) : "v"(a), "v"(u2), "v"(c));
    return d;
}
// acc += a * broadcast(hi(u2))
__device__ __forceinline__ v2f pk_fma_bh(v2f a, v2f u2, v2f c) {
    v2f d;
    asm("v_pk_fma_f32 %0, %1, %2, %3 op_sel:[0,1,0] op_sel_hi:[1,1,1]"
        : "=v"(d) : "v"(a), "v"(u2), "v"(c));
    return d;
}
__device__ __forceinline__ v2f pk_mul_bl(v2f a, v2f u2) {
    v2f d;
    asm("v_pk_mul_f32 %0, %1, %2 op_sel:[0,0] op_sel_hi:[1,0]"
        : "=v"(d) : "v"(a), "v"(u2));
    return d;
}
__device__ __forceinline__ v2f pk_mul_bh(v2f a, v2f u2) {
    v2f d;
    asm("v_pk_mul_f32 %0, %1, %2 op_sel:[0,1] op_sel_hi:[1,1]"
        : "=v"(d) : "v"(a), "v"(u2));
    return d;
}

__global__ __launch_bounds__(256, 4) void sinkhorn_kernel(
        const float* __restrict__ x, float* __restrict__ out, int nmat) {
    const int lane = threadIdx.x & 63;
    const int wave = threadIdx.x >> 6;
    const int mat  = blockIdx.x * 4 + wave;
    if (mat >= nmat) return;
    const int bi = lane >> 3;   // block-row 0..7 (lane bits 3-5)
    const int bj = lane & 7;    // block-col 0..7 (lane bits 0-2)

    const float4* __restrict__ xin = (const float4*)(x + (size_t)mat * 4096);

    // Load 8x8 block as 2 float4 per row, apply exp, keep as float2 pairs.
    v2f b2[8][4];
    #pragma unroll
    for (int r = 0; r < 8; ++r) {
        float4 lo = xin[(8 * bi + r) * 16 + 2 * bj + 0];
        float4 hi = xin[(8 * bi + r) * 16 + 2 * bj + 1];
        b2[r][0] = (v2f){__expf(lo.x), __expf(lo.y)};
        b2[r][1] = (v2f){__expf(lo.z), __expf(lo.w)};
        b2[r][2] = (v2f){__expf(hi.x), __expf(hi.y)};
        b2[r][3] = (v2f){__expf(hi.z), __expf(hi.w)};
    }

    // u for row pairs (2k,2k+1) packed; v for col pairs packed.
    v2f uu2[4], vv2[4];
    #pragma unroll
    for (int i = 0; i < 4; ++i) {
        uu2[i] = (v2f){1.0f, 1.0f};
        vv2[i] = (v2f){1.0f, 1.0f};
    }

    for (int it = 0; it < ITERS; ++it) {
        // ---- row phase: p_i = sum_j E[i,j] v_j ; u_i = rcp(p_i + eps) ----
        float p[8];
        #pragma unroll
        for (int r = 0; r < 8; ++r) {
            v2f s2 = pk_mul(b2[r][0], vv2[0]);
            s2 = pk_fma(b2[r][1], vv2[1], s2);
            s2 = pk_fma(b2[r][2], vv2[2], s2);
            s2 = pk_fma(b2[r][3], vv2[3], s2);
            p[r] = s2.x + s2.y;
        }
        // all-reduce across the 8 bj lanes (lane bits 0-2) — fused DPP adds
        #pragma unroll
        for (int r = 0; r < 8; ++r) p[r] = dpp_add<0xB1>(p[r]);   // quad_perm xor1
        #pragma unroll
        for (int r = 0; r < 8; ++r) p[r] = dpp_add<0x4E>(p[r]);   // quad_perm xor2
        #pragma unroll
        for (int r = 0; r < 8; ++r) p[r] = dpp_add<0x141>(p[r]);  // row_half_mirror = xor7
        #pragma unroll
        for (int k = 0; k < 4; ++k) {
            uu2[k].x = __builtin_amdgcn_rcpf(p[2 * k + 0] + EPS);
            uu2[k].y = __builtin_amdgcn_rcpf(p[2 * k + 1] + EPS);
        }

        // ---- col phase: q_j = sum_i E[i,j] u_i ; v_j = rcp(q_j + eps) ----
        // two interleaved accumulator sets (even rows / odd rows) for ILP
        v2f qe[4], qo[4];
        #pragma unroll
        for (int c = 0; c < 4; ++c) {
            qe[c] = pk_mul_bl(b2[0][c], uu2[0]);   // row 0 = lo(uu2[0])
            qo[c] = pk_mul_bh(b2[1][c], uu2[0]);   // row 1 = hi(uu2[0])
        }
        #pragma unroll
        for (int k = 1; k < 4; ++k) {
            #pragma unroll
            for (int c = 0; c < 4; ++c) {
                qe[c] = pk_fma_bl(b2[2 * k + 0][c], uu2[k], qe[c]);
                qo[c] = pk_fma_bh(b2[2 * k + 1][c], uu2[k], qo[c]);
            }
        }
        float q[8];
        #pragma unroll
        for (int c = 0; c < 4; ++c) {
            v2f s2 = pk_add(qe[c], qo[c]);
            q[2 * c + 0] = s2.x;
            q[2 * c + 1] = s2.y;
        }
        // all-reduce across the 8 bi lanes (lane bits 3-5) — all VALU
        #pragma unroll
        for (int c = 0; c < 8; ++c) q[c] = dpp_add<0x128>(q[c]);  // row_ror:8 = xor8
        #pragma unroll
        for (int c = 0; c < 8; ++c) q[c] = xadd16(q[c]);          // permlane16_swap
        #pragma unroll
        for (int c = 0; c < 8; ++c) q[c] = xadd32(q[c]);          // permlane32_swap
        #pragma unroll
        for (int c = 0; c < 4; ++c) {
            vv2[c].x = __builtin_amdgcn_rcpf(q[2 * c + 0] + EPS);
            vv2[c].y = __builtin_amdgcn_rcpf(q[2 * c + 1] + EPS);
        }
    }

    // ---- epilogue: out = E .* (u v^T) ----
    float4* __restrict__ o = (float4*)(out + (size_t)mat * 4096);
    #pragma unroll
    for (int r = 0; r < 8; ++r) {
        v2f u2 = (r & 1) ? (v2f){uu2[r >> 1].y, uu2[r >> 1].y}
                         : (v2f){uu2[r >> 1].x, uu2[r >> 1].x};
        v2f w0 = pk_mul(b2[r][0], pk_mul(vv2[0], u2));
        v2f w1 = pk_mul(b2[r][1], pk_mul(vv2[1], u2));
        v2f w2 = pk_mul(b2[r][2], pk_mul(vv2[2], u2));
        v2f w3 = pk_mul(b2[r][3], pk_mul(vv2[3], u2));
        float4 lo, hi;
        lo.x = w0.x; lo.y = w0.y; lo.z = w1.x; lo.w = w1.y;
        hi.x = w2.x; hi.y = w2.y; hi.z = w3.x; hi.w = w3.y;
        o[(8 * bi + r) * 16 + 2 * bj + 0] = lo;
        o[(8 * bi + r) * 16 + 2 * bj + 1] = hi;
    }
}

extern "C" void kernel_launch(void* const* d_in, const int* in_sizes, int n_in,
                              void* d_out, int out_size, void* d_ws, size_t ws_size,
                              hipStream_t stream) {
    const float* x = (const float*)d_in[0];
    float* out = (float*)d_out;
    const int nmat = in_sizes[0] / 4096;          // 8192 matrices of 64x64
    const int blocks = (nmat + 3) / 4;            // 4 matrices (waves) per block
    sinkhorn_kernel<<<blocks, 256, 0, stream>>>(x, out, nmat);
}